// Round 1
// baseline (16303.156 us; speedup 1.0000x reference)
//
#include <hip/hip_runtime.h>
#include <hip/hip_bf16.h>

// Problem: B=1024, L=100, D=512, NUM_LAYERS=2
// Inputs: x[B,L,D] f32, text_len[B] i32, W_r[1024,512], b_r[512], W_u, b_u, W_o, b_o
// Outputs: x'[B,L,D] f32 then seq_emb[B,D] f32, concatenated in d_out.

#define B_ 1024
#define L_ 100
#define D_ 512
#define ROWS (B_*L_)           // 102400
#define XELEMS ((size_t)ROWS*D_) // 52428800

// ---------------- positional encoding ----------------
__global__ void pe_kernel(float* __restrict__ pe) {
    int idx = blockIdx.x * 256 + threadIdx.x;
    if (idx >= L_ * D_) return;
    int l = idx >> 9;          // /512
    int d = idx & 511;
    int i = d >> 1;
    // div = exp(-(2i)*ln(10000)/512)
    float div = expf((float)(2 * i) * (-9.210340371976184f / 512.0f));
    float angle = (float)l * div;
    pe[idx] = (d & 1) ? cosf(angle) : sinf(angle);
}

// ---------------- fused score+softmax+message ----------------
// one block per (b,l) row; 128 threads
__global__ void __launch_bounds__(128) attn_msg_kernel(
    const float* __restrict__ x, const float* __restrict__ pe,
    const int* __restrict__ text_len, __hip_bfloat16* __restrict__ msg)
{
    const int b = blockIdx.y, l = blockIdx.x;
    const int tid = threadIdx.x;
    const int len = text_len[b];
    __shared__ float xpl[D_];
    __shared__ float sc[128];
    __shared__ float red[128];
    const float* xb = x + (size_t)b * L_ * D_;

    for (int d = tid; d < D_; d += 128)
        xpl[d] = xb[(size_t)l * D_ + d] + pe[l * D_ + d];
    __syncthreads();

    const int m = tid;
    float s = -INFINITY;
    if (m < L_) {
        if (l < len && m < len) {
            const float* xm = xb + (size_t)m * D_;
            const float* pem = pe + m * D_;
            float acc = 0.f;
            for (int d = 0; d < D_; d += 4) {
                float4 xv = *(const float4*)(xm + d);
                float4 pv = *(const float4*)(pem + d);
                float4 xp4 = *(const float4*)(xpl + d);
                acc += xp4.x * (xv.x + pv.x);
                acc += xp4.y * (xv.y + pv.y);
                acc += xp4.z * (xv.z + pv.z);
                acc += xp4.w * (xv.w + pv.w);
            }
            s = acc;
        } else {
            s = 1e-10f;   // MASK_FILL (reference uses 1e-10, not -inf)
        }
    }
    sc[tid] = s;
    red[tid] = s;
    __syncthreads();
    // max reduce over 128 (inactive lanes hold -inf)
    for (int off = 64; off > 0; off >>= 1) {
        if (tid < off) red[tid] = fmaxf(red[tid], red[tid + off]);
        __syncthreads();
    }
    float mx = red[0];
    __syncthreads();
    float e = (tid < L_) ? expf(sc[tid] - mx) : 0.f;
    red[tid] = e;
    __syncthreads();
    for (int off = 64; off > 0; off >>= 1) {
        if (tid < off) red[tid] += red[tid + off];
        __syncthreads();
    }
    float inv = 1.f / red[0];
    __syncthreads();
    sc[tid] = e * inv;   // attention weights
    __syncthreads();

    // message[l,:] = sum_m attn[m] * x[b,m,:]
    for (int d = tid; d < D_; d += 128) {
        float acc = 0.f;
        #pragma unroll 4
        for (int mm = 0; mm < L_; ++mm)
            acc += sc[mm] * xb[(size_t)mm * D_ + d];
        msg[((size_t)b * L_ + l) * D_ + d] = __float2bfloat16(acc);
    }
}

// ---------------- GEMM 1: update & reset gates (fused epilogue) ----------------
// out[r,c]: u = sigmoid(si @ W_u + b_u), rr = sigmoid(si @ W_r + b_r)
// si = [msg | x]   (K = 1024)
// stores upd = bf16(u), xr = bf16(x * rr)
__global__ void __launch_bounds__(256) gates_ur_kernel(
    const __hip_bfloat16* __restrict__ msg, const float* __restrict__ x,
    const float* __restrict__ Wu, const float* __restrict__ Wr,
    const float* __restrict__ bu, const float* __restrict__ br,
    __hip_bfloat16* __restrict__ upd, __hip_bfloat16* __restrict__ xr)
{
    __shared__ float As[16][68];
    __shared__ float Bu[16][64];
    __shared__ float Br[16][64];
    const int tid = threadIdx.x;
    const int tx = tid & 15, ty = tid >> 4;
    const int row0 = blockIdx.x * 64;
    const int col0 = blockIdx.y * 64;
    float accu[4][4] = {};
    float accr[4][4] = {};

    for (int kc = 0; kc < 1024; kc += 16) {
        for (int t = tid; t < 64 * 16; t += 256) {
            int r = t >> 4, k = t & 15;
            int gr = row0 + r, gk = kc + k;
            float v = (gk < D_) ? __bfloat162float(msg[(size_t)gr * D_ + gk])
                                : x[(size_t)gr * D_ + gk - D_];
            As[k][r] = v;
        }
        for (int t = tid; t < 16 * 64; t += 256) {
            int k = t >> 6, n = t & 63;
            Bu[k][n] = Wu[(size_t)(kc + k) * D_ + col0 + n];
            Br[k][n] = Wr[(size_t)(kc + k) * D_ + col0 + n];
        }
        __syncthreads();
        #pragma unroll
        for (int kk = 0; kk < 16; ++kk) {
            float4 av = *(const float4*)&As[kk][ty * 4];
            float4 buv = *(const float4*)&Bu[kk][tx * 4];
            float4 brv = *(const float4*)&Br[kk][tx * 4];
            float a[4] = {av.x, av.y, av.z, av.w};
            float bu_[4] = {buv.x, buv.y, buv.z, buv.w};
            float br_[4] = {brv.x, brv.y, brv.z, brv.w};
            #pragma unroll
            for (int i = 0; i < 4; ++i)
                #pragma unroll
                for (int j = 0; j < 4; ++j) {
                    accu[i][j] += a[i] * bu_[j];
                    accr[i][j] += a[i] * br_[j];
                }
        }
        __syncthreads();
    }
    #pragma unroll
    for (int i = 0; i < 4; ++i) {
        int r = row0 + ty * 4 + i;
        size_t base = (size_t)r * D_ + col0 + tx * 4;
        float4 xv = *(const float4*)(x + base);
        float xvv[4] = {xv.x, xv.y, xv.z, xv.w};
        #pragma unroll
        for (int j = 0; j < 4; ++j) {
            int c = col0 + tx * 4 + j;
            float pu = accu[i][j] + bu[c];
            float pr = accr[i][j] + br[c];
            float u = 1.f / (1.f + expf(-pu));
            float rr = 1.f / (1.f + expf(-pr));
            upd[base + j] = __float2bfloat16(u);
            xr[base + j] = __float2bfloat16(xvv[j] * rr);
        }
    }
}

// ---------------- GEMM 2: candidate + GRU combine (fused epilogue) ----------------
// so = [msg | xr]  (K = 1024); cand = tanh(so @ W_o + b_o)
// x = x*(1-u) + cand*u   (in place on working x)
__global__ void __launch_bounds__(256) gates_o_kernel(
    const __hip_bfloat16* __restrict__ msg, const __hip_bfloat16* __restrict__ xr,
    const float* __restrict__ Wo, const float* __restrict__ bo,
    const __hip_bfloat16* __restrict__ upd, float* __restrict__ x)
{
    __shared__ float As[16][68];
    __shared__ float Bo[16][64];
    const int tid = threadIdx.x;
    const int tx = tid & 15, ty = tid >> 4;
    const int row0 = blockIdx.x * 64;
    const int col0 = blockIdx.y * 64;
    float acc[4][4] = {};

    for (int kc = 0; kc < 1024; kc += 16) {
        for (int t = tid; t < 64 * 16; t += 256) {
            int r = t >> 4, k = t & 15;
            int gr = row0 + r, gk = kc + k;
            float v = (gk < D_) ? __bfloat162float(msg[(size_t)gr * D_ + gk])
                                : __bfloat162float(xr[(size_t)gr * D_ + gk - D_]);
            As[k][r] = v;
        }
        for (int t = tid; t < 16 * 64; t += 256) {
            int k = t >> 6, n = t & 63;
            Bo[k][n] = Wo[(size_t)(kc + k) * D_ + col0 + n];
        }
        __syncthreads();
        #pragma unroll
        for (int kk = 0; kk < 16; ++kk) {
            float4 av = *(const float4*)&As[kk][ty * 4];
            float4 bov = *(const float4*)&Bo[kk][tx * 4];
            float a[4] = {av.x, av.y, av.z, av.w};
            float bo_[4] = {bov.x, bov.y, bov.z, bov.w};
            #pragma unroll
            for (int i = 0; i < 4; ++i)
                #pragma unroll
                for (int j = 0; j < 4; ++j)
                    acc[i][j] += a[i] * bo_[j];
        }
        __syncthreads();
    }
    #pragma unroll
    for (int i = 0; i < 4; ++i) {
        int r = row0 + ty * 4 + i;
        size_t base = (size_t)r * D_ + col0 + tx * 4;
        float4 xv = *(const float4*)(x + base);
        float xvv[4] = {xv.x, xv.y, xv.z, xv.w};
        float out[4];
        #pragma unroll
        for (int j = 0; j < 4; ++j) {
            int c = col0 + tx * 4 + j;
            float cand = tanhf(acc[i][j] + bo[c]);
            float u = __bfloat162float(upd[base + j]);
            out[j] = xvv[j] * (1.f - u) + cand * u;
        }
        *(float4*)(x + base) = make_float4(out[0], out[1], out[2], out[3]);
    }
}

// ---------------- masked mean pooling ----------------
__global__ void __launch_bounds__(256) pool_kernel(
    const float* __restrict__ x, const int* __restrict__ text_len,
    float* __restrict__ seq)
{
    int b = blockIdx.x;
    int len = text_len[b];
    float invlen = 1.f / (float)len;
    const float* xb = x + (size_t)b * L_ * D_;
    for (int d = threadIdx.x; d < D_; d += 256) {
        float acc = 0.f;
        for (int l = 0; l < len; ++l)
            acc += xb[(size_t)l * D_ + d];
        seq[(size_t)b * D_ + d] = acc * invlen;
    }
}

extern "C" void kernel_launch(void* const* d_in, const int* in_sizes, int n_in,
                              void* d_out, int out_size, void* d_ws, size_t ws_size,
                              hipStream_t stream) {
    const float* x_in = (const float*)d_in[0];
    const int* text_len = (const int*)d_in[1];
    const float* W_r = (const float*)d_in[2];
    const float* b_r = (const float*)d_in[3];
    const float* W_u = (const float*)d_in[4];
    const float* b_u = (const float*)d_in[5];
    const float* W_o = (const float*)d_in[6];
    const float* b_o = (const float*)d_in[7];

    float* xwork = (float*)d_out;                 // working x lives in d_out
    float* seq_out = (float*)d_out + XELEMS;

    char* ws = (char*)d_ws;
    float* pe = (float*)ws;                                        // 204800 B
    __hip_bfloat16* msg = (__hip_bfloat16*)(ws + 204800);          // 104857600 B
    __hip_bfloat16* xr  = (__hip_bfloat16*)(ws + 204800 + 104857600ull);
    __hip_bfloat16* upd = (__hip_bfloat16*)(ws + 204800 + 2ull * 104857600ull);

    // init working x = input x
    hipMemcpyAsync(xwork, x_in, XELEMS * sizeof(float), hipMemcpyDeviceToDevice, stream);

    pe_kernel<<<(L_ * D_ + 255) / 256, 256, 0, stream>>>(pe);

    for (int layer = 0; layer < 2; ++layer) {
        attn_msg_kernel<<<dim3(L_, B_), 128, 0, stream>>>(xwork, pe, text_len, msg);
        gates_ur_kernel<<<dim3(ROWS / 64, D_ / 64), 256, 0, stream>>>(
            msg, xwork, W_u, W_r, b_u, b_r, upd, xr);
        gates_o_kernel<<<dim3(ROWS / 64, D_ / 64), 256, 0, stream>>>(
            msg, xr, W_o, b_o, upd, xwork);
    }
    pool_kernel<<<B_, 256, 0, stream>>>(xwork, text_len, seq_out);
}

// Round 2
// 2407.208 us; speedup vs baseline: 6.7726x; 6.7726x over previous
//
#include <hip/hip_runtime.h>
#include <hip/hip_bf16.h>

// B=1024, L=100, D=512, 2 layers. Outputs: x'[B,L,D] f32 then seq_emb[B,D] f32.
#define B_ 1024
#define L_ 100
#define D_ 512
#define LP 128                    // padded L for MFMA tiles
#define ROWS (B_*L_)              // 102400
#define XELEMS ((size_t)ROWS*D_)  // 52428800
#define HB 512                    // batches per half (attention/prep)
#define HR (HB*L_)                // rows per half = 51200

typedef __attribute__((ext_vector_type(8))) short short8;
typedef __attribute__((ext_vector_type(4))) float f32x4;

__device__ __forceinline__ short f2bf(float f) {
    __hip_bfloat16 h = __float2bfloat16(f);
    return *reinterpret_cast<short*>(&h);
}

__device__ __forceinline__ void cp16(void* lds, const void* g) {
    __builtin_amdgcn_global_load_lds(
        (const __attribute__((address_space(1))) unsigned int*)g,
        (__attribute__((address_space(3))) unsigned int*)lds, 16, 0, 0);
}

__device__ __forceinline__ f32x4 mfma16(short8 a, short8 b, f32x4 c) {
    return __builtin_amdgcn_mfma_f32_16x16x32_bf16(a, b, c, 0, 0, 0);
}

// ---------------- positional encoding ----------------
__global__ __launch_bounds__(256) void pe_kernel(float* __restrict__ pe) {
    int idx = blockIdx.x * 256 + threadIdx.x;
    if (idx >= L_ * D_) return;
    int l = idx >> 9;
    int d = idx & 511;
    int i = d >> 1;
    float div = __expf((float)(2 * i) * (-9.210340371976184f / 512.0f));
    float angle = (float)l * div;
    pe[idx] = (d & 1) ? __cosf(angle) : __sinf(angle);
}

// ---------------- weight transpose+cvt: W[k][n] f32 -> Wt[n][k] bf16 ----------------
__global__ __launch_bounds__(256) void cvtw_kernel(const float* __restrict__ W,
                                                   __hip_bfloat16* __restrict__ Wt) {
    int idx = blockIdx.x * 256 + threadIdx.x;   // over 512*1024
    int n = idx >> 10, k = idx & 1023;
    Wt[idx] = __float2bfloat16(W[(size_t)k * D_ + n]);
}

// ---------------- per-batch transpose: x[b][l][d] f32 -> xT[bl][d][l(pad128)] bf16 ----
__global__ __launch_bounds__(256) void prep_xt_kernel(const float* __restrict__ x,
                                                      __hip_bfloat16* __restrict__ xTb,
                                                      int bh) {
    const int bl = blockIdx.y;            // local batch 0..511
    const int b = bh * HB + bl;
    const int d0 = blockIdx.x * 64;
    __shared__ __hip_bfloat16 t[64][66];
    const float* xb = x + (size_t)b * L_ * D_;
    const int tid = threadIdx.x;
    for (int l0 = 0; l0 < LP; l0 += 64) {
        int l_loc = tid >> 2;
        int dq = tid & 3;
        #pragma unroll
        for (int i = 0; i < 4; ++i) {
            int d_loc = (dq * 4 + i) * 4;
            int l = l0 + l_loc;
            float4 v = (l < L_) ? *(const float4*)(xb + (size_t)l * D_ + d0 + d_loc)
                                : make_float4(0.f, 0.f, 0.f, 0.f);
            t[l_loc][d_loc + 0] = __float2bfloat16(v.x);
            t[l_loc][d_loc + 1] = __float2bfloat16(v.y);
            t[l_loc][d_loc + 2] = __float2bfloat16(v.z);
            t[l_loc][d_loc + 3] = __float2bfloat16(v.w);
        }
        __syncthreads();
        int dl = tid >> 2, seg = tid & 3;
        short8 lo, hi;
        #pragma unroll
        for (int j = 0; j < 8; ++j) {
            __hip_bfloat16 a = t[seg * 16 + j][dl];
            __hip_bfloat16 bswap = t[seg * 16 + 8 + j][dl];
            lo[j] = *reinterpret_cast<short*>(&a);
            hi[j] = *reinterpret_cast<short*>(&bswap);
        }
        __hip_bfloat16* dst = xTb + ((size_t)bl * D_ + d0 + dl) * LP + l0 + seg * 16;
        *(short8*)dst = lo;
        *(short8*)(dst + 8) = hi;
        __syncthreads();
    }
}

// ---------------- fused attention: block per batch, 4 waves, MFMA ----------------
__global__ __launch_bounds__(256) void attn_kernel(
    const float* __restrict__ x, const float* __restrict__ pe,
    const int* __restrict__ text_len, const __hip_bfloat16* __restrict__ xTb,
    __hip_bfloat16* __restrict__ msg, int bh)
{
    __shared__ __align__(16) char sm[16384 + 32768];
    char* XP = sm;             // [128][64] bf16, swizzled, rowbytes=128
    char* P  = sm + 16384;     // [128][128] bf16, swizzled, rowbytes=256
    const int bl = blockIdx.x;
    const int b = bh * HB + bl;
    const int len = text_len[b];
    const int tid = threadIdx.x;
    const int w = tid >> 6, g = (tid >> 4) & 3, cl = tid & 15;
    const float* xb = x + (size_t)b * L_ * D_;

    f32x4 accS[2][8];
    const f32x4 fz = {0.f, 0.f, 0.f, 0.f};
    #pragma unroll
    for (int i = 0; i < 2; ++i)
        #pragma unroll
        for (int j = 0; j < 8; ++j) accS[i][j] = fz;

    // ---- phase A: S = xp @ xp^T ----
    for (int kc = 0; kc < D_; kc += 64) {
        #pragma unroll
        for (int i = 0; i < 4; ++i) {
            int c = tid + 256 * i;
            int row = c >> 3, k8d = c & 7;
            int k = kc + 8 * (k8d ^ (row & 7));
            short8 h;
            if (row < L_) {
                const float* px = xb + (size_t)row * D_ + k;
                const float* pp = pe + row * D_ + k;
                float4 a0 = *(const float4*)px, a1 = *(const float4*)(px + 4);
                float4 b0 = *(const float4*)pp, b1 = *(const float4*)(pp + 4);
                h[0] = f2bf(a0.x + b0.x); h[1] = f2bf(a0.y + b0.y);
                h[2] = f2bf(a0.z + b0.z); h[3] = f2bf(a0.w + b0.w);
                h[4] = f2bf(a1.x + b1.x); h[5] = f2bf(a1.y + b1.y);
                h[6] = f2bf(a1.z + b1.z); h[7] = f2bf(a1.w + b1.w);
            } else {
                #pragma unroll
                for (int q = 0; q < 8; ++q) h[q] = 0;
            }
            *(short8*)(XP + row * 128 + 16 * k8d) = h;
        }
        __syncthreads();
        #pragma unroll
        for (int kt = 0; kt < 2; ++kt) {
            short8 a[2];
            #pragma unroll
            for (int rt = 0; rt < 2; ++rt) {
                int r = 32 * w + 16 * rt + cl;
                a[rt] = *(const short8*)(XP + r * 128 + ((16 * g + 64 * kt) ^ ((r & 7) << 4)));
            }
            #pragma unroll
            for (int ct = 0; ct < 8; ++ct) {
                int m = 16 * ct + cl;
                short8 bb = *(const short8*)(XP + m * 128 + ((16 * g + 64 * kt) ^ ((m & 7) << 4)));
                accS[0][ct] = mfma16(a[0], bb, accS[0][ct]);
                accS[1][ct] = mfma16(a[1], bb, accS[1][ct]);
            }
        }
        __syncthreads();
    }

    // ---- phase B: masked softmax (reference MASK_FILL=1e-10, pads excluded) ----
    #pragma unroll
    for (int rt = 0; rt < 2; ++rt) {
        #pragma unroll
        for (int reg = 0; reg < 4; ++reg) {
            int rl = 32 * w + 16 * rt + 4 * g + reg;
            float s[8];
            #pragma unroll
            for (int ct = 0; ct < 8; ++ct) {
                int col = 16 * ct + cl;
                float v = accS[rt][ct][reg];
                if (col >= L_) v = -INFINITY;              // padding: excluded
                else if (rl >= len || col >= len) v = 1e-10f;  // MASK_FILL
                s[ct] = v;
            }
            float mx = s[0];
            #pragma unroll
            for (int ct = 1; ct < 8; ++ct) mx = fmaxf(mx, s[ct]);
            mx = fmaxf(mx, __shfl_xor(mx, 1));
            mx = fmaxf(mx, __shfl_xor(mx, 2));
            mx = fmaxf(mx, __shfl_xor(mx, 4));
            mx = fmaxf(mx, __shfl_xor(mx, 8));
            float e[8], sum = 0.f;
            #pragma unroll
            for (int ct = 0; ct < 8; ++ct) { e[ct] = __expf(s[ct] - mx); sum += e[ct]; }
            sum += __shfl_xor(sum, 1);
            sum += __shfl_xor(sum, 2);
            sum += __shfl_xor(sum, 4);
            sum += __shfl_xor(sum, 8);
            float inv = 1.f / sum;
            #pragma unroll
            for (int ct = 0; ct < 8; ++ct) {
                int col = 16 * ct + cl;
                *(short*)(P + rl * 256 + ((col * 2) ^ ((rl & 7) << 4))) = f2bf(e[ct] * inv);
            }
        }
    }
    // P rows [32w,32w+32) are written and read only by wave w: no barrier needed.

    // ---- phase C: message = P @ x  (B from precomputed x^T bf16) ----
    const __hip_bfloat16* xT = xTb + (size_t)bl * D_ * LP;
    for (int nc = 0; nc < 4; ++nc) {
        f32x4 accM[2][8];
        #pragma unroll
        for (int i = 0; i < 2; ++i)
            #pragma unroll
            for (int j = 0; j < 8; ++j) accM[i][j] = fz;
        #pragma unroll
        for (int kt = 0; kt < 4; ++kt) {
            short8 a[2];
            #pragma unroll
            for (int rt = 0; rt < 2; ++rt) {
                int r = 32 * w + 16 * rt + cl;
                a[rt] = *(const short8*)(P + r * 256 + ((16 * g + 64 * kt) ^ ((r & 7) << 4)));
            }
            #pragma unroll
            for (int nt = 0; nt < 8; ++nt) {
                int d = nc * 128 + nt * 16 + cl;
                short8 bb = *(const short8*)(xT + (size_t)d * LP + 8 * g + 32 * kt);
                accM[0][nt] = mfma16(a[0], bb, accM[0][nt]);
                accM[1][nt] = mfma16(a[1], bb, accM[1][nt]);
            }
        }
        #pragma unroll
        for (int rt = 0; rt < 2; ++rt) {
            #pragma unroll
            for (int nt = 0; nt < 8; ++nt) {
                #pragma unroll
                for (int reg = 0; reg < 4; ++reg) {
                    int rl = 32 * w + 16 * rt + 4 * g + reg;
                    if (rl < L_) {
                        int d = nc * 128 + nt * 16 + cl;
                        msg[((size_t)b * L_ + rl) * D_ + d] = __float2bfloat16(accM[rt][nt][reg]);
                    }
                }
            }
        }
    }
}

// ---------------- gates u,r: dual-B MFMA GEMM, A=[msg|x], K=1024 ----------------
__global__ __launch_bounds__(256) void gates_ur_kernel(
    const __hip_bfloat16* __restrict__ msg, const float* __restrict__ x,
    const __hip_bfloat16* __restrict__ Wut, const __hip_bfloat16* __restrict__ Wrt,
    const float* __restrict__ gbu, const float* __restrict__ gbr,
    __hip_bfloat16* __restrict__ upd, __hip_bfloat16* __restrict__ xr, int rh)
{
    __shared__ __align__(16) char sm[3 * 16384];
    char* As  = sm;
    char* sBu = sm + 16384;
    char* sBr = sm + 32768;
    const int tid = threadIdx.x;
    const int w = tid >> 6, g = (tid >> 4) & 3, cl = tid & 15;
    const int wr = w >> 1, wc = w & 1;
    const size_t R0 = (size_t)rh * HR + (size_t)blockIdx.x * 128;  // global row
    const int lr0 = blockIdx.x * 128;                               // local row
    const int col0 = blockIdx.y * 128;
    f32x4 au[4][4], ar[4][4];
    const f32x4 fz = {0.f, 0.f, 0.f, 0.f};
    #pragma unroll
    for (int i = 0; i < 4; ++i)
        #pragma unroll
        for (int j = 0; j < 4; ++j) { au[i][j] = fz; ar[i][j] = fz; }

    for (int kc = 0; kc < 1024; kc += 64) {
        if (kc < 512) {
            const __hip_bfloat16* src = msg + R0 * D_ + kc;
            #pragma unroll
            for (int i = 0; i < 4; ++i) {
                int c = tid + 256 * i, row = c >> 3, k8 = (c & 7) ^ (row & 7);
                cp16(As + c * 16, src + (size_t)row * D_ + 8 * k8);
            }
        } else {
            const float* src = x + R0 * D_ + (kc - 512);
            #pragma unroll
            for (int i = 0; i < 4; ++i) {
                int c = tid + 256 * i, row = c >> 3, k8 = (c & 7) ^ (row & 7);
                const float* p = src + (size_t)row * D_ + 8 * k8;
                float4 v0 = *(const float4*)p, v1 = *(const float4*)(p + 4);
                short8 h;
                h[0] = f2bf(v0.x); h[1] = f2bf(v0.y); h[2] = f2bf(v0.z); h[3] = f2bf(v0.w);
                h[4] = f2bf(v1.x); h[5] = f2bf(v1.y); h[6] = f2bf(v1.z); h[7] = f2bf(v1.w);
                *(short8*)(As + c * 16) = h;
            }
        }
        const __hip_bfloat16* su = Wut + (size_t)col0 * 1024 + kc;
        const __hip_bfloat16* sr = Wrt + (size_t)col0 * 1024 + kc;
        #pragma unroll
        for (int i = 0; i < 4; ++i) {
            int c = tid + 256 * i, row = c >> 3, k8 = (c & 7) ^ (row & 7);
            cp16(sBu + c * 16, su + (size_t)row * 1024 + 8 * k8);
            cp16(sBr + c * 16, sr + (size_t)row * 1024 + 8 * k8);
        }
        __syncthreads();
        #pragma unroll
        for (int kt = 0; kt < 2; ++kt) {
            short8 a[4], bu_[4], br_[4];
            #pragma unroll
            for (int t = 0; t < 4; ++t) {
                int r = 64 * wr + 16 * t + cl;
                a[t] = *(const short8*)(As + r * 128 + ((16 * g + 64 * kt) ^ ((r & 7) << 4)));
                int n = 64 * wc + 16 * t + cl;
                bu_[t] = *(const short8*)(sBu + n * 128 + ((16 * g + 64 * kt) ^ ((n & 7) << 4)));
                br_[t] = *(const short8*)(sBr + n * 128 + ((16 * g + 64 * kt) ^ ((n & 7) << 4)));
            }
            #pragma unroll
            for (int i = 0; i < 4; ++i)
                #pragma unroll
                for (int j = 0; j < 4; ++j) {
                    au[i][j] = mfma16(a[i], bu_[j], au[i][j]);
                    ar[i][j] = mfma16(a[i], br_[j], ar[i][j]);
                }
        }
        __syncthreads();
    }
    #pragma unroll
    for (int i = 0; i < 4; ++i) {
        #pragma unroll
        for (int j = 0; j < 4; ++j) {
            int col = col0 + 64 * wc + 16 * j + cl;
            float bub = gbu[col], brb = gbr[col];
            #pragma unroll
            for (int reg = 0; reg < 4; ++reg) {
                int lrow = lr0 + 64 * wr + 16 * i + 4 * g + reg;
                size_t grow = (size_t)rh * HR + lrow;
                float u = 1.f / (1.f + __expf(-(au[i][j][reg] + bub)));
                float r = 1.f / (1.f + __expf(-(ar[i][j][reg] + brb)));
                float xv = x[grow * D_ + col];
                upd[(size_t)lrow * D_ + col] = __float2bfloat16(u);
                xr[(size_t)lrow * D_ + col] = __float2bfloat16(xv * r);
            }
        }
    }
}

// ---------------- gates o: MFMA GEMM A=[msg|xr], epilogue GRU combine ----------------
__global__ __launch_bounds__(256) void gates_o_kernel(
    const __hip_bfloat16* __restrict__ msg, const __hip_bfloat16* __restrict__ xr,
    const __hip_bfloat16* __restrict__ Wot, const float* __restrict__ gbo,
    const __hip_bfloat16* __restrict__ upd, float* __restrict__ x, int rh)
{
    __shared__ __align__(16) char sm[2 * 16384];
    char* As  = sm;
    char* sBo = sm + 16384;
    const int tid = threadIdx.x;
    const int w = tid >> 6, g = (tid >> 4) & 3, cl = tid & 15;
    const int wr = w >> 1, wc = w & 1;
    const size_t R0 = (size_t)rh * HR + (size_t)blockIdx.x * 128;
    const int lr0 = blockIdx.x * 128;
    const int col0 = blockIdx.y * 128;
    f32x4 acc[4][4];
    const f32x4 fz = {0.f, 0.f, 0.f, 0.f};
    #pragma unroll
    for (int i = 0; i < 4; ++i)
        #pragma unroll
        for (int j = 0; j < 4; ++j) acc[i][j] = fz;

    for (int kc = 0; kc < 1024; kc += 64) {
        const __hip_bfloat16* src = (kc < 512) ? (msg + R0 * D_ + kc)
                                               : (xr + (size_t)lr0 * D_ + (kc - 512));
        #pragma unroll
        for (int i = 0; i < 4; ++i) {
            int c = tid + 256 * i, row = c >> 3, k8 = (c & 7) ^ (row & 7);
            cp16(As + c * 16, src + (size_t)row * D_ + 8 * k8);
        }
        const __hip_bfloat16* so = Wot + (size_t)col0 * 1024 + kc;
        #pragma unroll
        for (int i = 0; i < 4; ++i) {
            int c = tid + 256 * i, row = c >> 3, k8 = (c & 7) ^ (row & 7);
            cp16(sBo + c * 16, so + (size_t)row * 1024 + 8 * k8);
        }
        __syncthreads();
        #pragma unroll
        for (int kt = 0; kt < 2; ++kt) {
            short8 a[4], bo_[4];
            #pragma unroll
            for (int t = 0; t < 4; ++t) {
                int r = 64 * wr + 16 * t + cl;
                a[t] = *(const short8*)(As + r * 128 + ((16 * g + 64 * kt) ^ ((r & 7) << 4)));
                int n = 64 * wc + 16 * t + cl;
                bo_[t] = *(const short8*)(sBo + n * 128 + ((16 * g + 64 * kt) ^ ((n & 7) << 4)));
            }
            #pragma unroll
            for (int i = 0; i < 4; ++i)
                #pragma unroll
                for (int j = 0; j < 4; ++j)
                    acc[i][j] = mfma16(a[i], bo_[j], acc[i][j]);
        }
        __syncthreads();
    }
    #pragma unroll
    for (int i = 0; i < 4; ++i) {
        #pragma unroll
        for (int j = 0; j < 4; ++j) {
            int col = col0 + 64 * wc + 16 * j + cl;
            float bob = gbo[col];
            #pragma unroll
            for (int reg = 0; reg < 4; ++reg) {
                int lrow = lr0 + 64 * wr + 16 * i + 4 * g + reg;
                size_t grow = (size_t)rh * HR + lrow;
                float cand = tanhf(acc[i][j][reg] + bob);
                float u = __bfloat162float(upd[(size_t)lrow * D_ + col]);
                float xv = x[grow * D_ + col];
                x[grow * D_ + col] = xv + u * (cand - xv);
            }
        }
    }
}

// ---------------- masked mean pooling ----------------
__global__ __launch_bounds__(256) void pool_kernel(
    const float* __restrict__ x, const int* __restrict__ text_len,
    float* __restrict__ seq)
{
    int b = blockIdx.x;
    int len = text_len[b];
    float invlen = 1.f / (float)len;
    const float* xb = x + (size_t)b * L_ * D_;
    for (int d = threadIdx.x; d < D_; d += 256) {
        float acc = 0.f;
        for (int l = 0; l < len; ++l)
            acc += xb[(size_t)l * D_ + d];
        seq[(size_t)b * D_ + d] = acc * invlen;
    }
}

extern "C" void kernel_launch(void* const* d_in, const int* in_sizes, int n_in,
                              void* d_out, int out_size, void* d_ws, size_t ws_size,
                              hipStream_t stream) {
    const float* x_in = (const float*)d_in[0];
    const int* text_len = (const int*)d_in[1];
    const float* W_r = (const float*)d_in[2];
    const float* b_r = (const float*)d_in[3];
    const float* W_u = (const float*)d_in[4];
    const float* b_u = (const float*)d_in[5];
    const float* W_o = (const float*)d_in[6];
    const float* b_o = (const float*)d_in[7];

    float* xwork = (float*)d_out;
    float* seq_out = (float*)d_out + XELEMS;

    char* ws = (char*)d_ws;
    float* pe            = (float*)ws;                                    // 204800 B
    __hip_bfloat16* Wut  = (__hip_bfloat16*)(ws + 204800);                // 1 MiB
    __hip_bfloat16* Wrt  = (__hip_bfloat16*)(ws + 204800 + 1048576ull);
    __hip_bfloat16* Wot  = (__hip_bfloat16*)(ws + 204800 + 2097152ull);
    __hip_bfloat16* msg  = (__hip_bfloat16*)(ws + 3350528ull);            // 104857600 B
    __hip_bfloat16* upd  = (__hip_bfloat16*)(ws + 108208128ull);          // 52428800 B
    char* R1 = ws + 160636928ull;                                         // 67108864 B
    __hip_bfloat16* xTb = (__hip_bfloat16*)R1;   // [512][512][128] bf16 (per batch-half)
    __hip_bfloat16* xr  = (__hip_bfloat16*)R1;   // [51200][512] bf16 (per row-half)

    hipMemcpyAsync(xwork, x_in, XELEMS * sizeof(float), hipMemcpyDeviceToDevice, stream);
    pe_kernel<<<(L_ * D_ + 255) / 256, 256, 0, stream>>>(pe);
    cvtw_kernel<<<2048, 256, 0, stream>>>(W_u, Wut);
    cvtw_kernel<<<2048, 256, 0, stream>>>(W_r, Wrt);
    cvtw_kernel<<<2048, 256, 0, stream>>>(W_o, Wot);

    for (int layer = 0; layer < 2; ++layer) {
        for (int bh = 0; bh < 2; ++bh) {
            prep_xt_kernel<<<dim3(8, HB), 256, 0, stream>>>(xwork, xTb, bh);
            attn_kernel<<<HB, 256, 0, stream>>>(xwork, pe, text_len, xTb, msg, bh);
        }
        for (int rh = 0; rh < 2; ++rh) {
            gates_ur_kernel<<<dim3(HR / 128, 4), 256, 0, stream>>>(
                msg, xwork, Wut, Wrt, b_u, b_r, upd, xr, rh);
            gates_o_kernel<<<dim3(HR / 128, 4), 256, 0, stream>>>(
                msg, xr, Wot, b_o, upd, xwork, rh);
        }
    }
    pool_kernel<<<B_, 256, 0, stream>>>(xwork, text_len, seq_out);
}